// Round 15
// baseline (125.765 us; speedup 1.0000x reference)
//
#include <hip/hip_runtime.h>

#define TT 200
#define FF 32
#define HH 50
#define PITCH 68   // u32 pitch of row-pair rows: writes 2-way banks (free)

typedef _Float16 half8 __attribute__((ext_vector_type(8)));   // 8 f16 = 4 VGPR
typedef __attribute__((ext_vector_type(4))) float f32x4;
typedef __attribute__((ext_vector_type(4))) unsigned int uint32x4;

// tanh(x) = 1 - 2/(exp2(2*log2e*x)+1)
__device__ __forceinline__ float fast_tanh(float x) {
    float e = exp2f(2.885390082f * x);
    return fmaf(-2.0f, __builtin_amdgcn_rcpf(e + 1.0f), 1.0f);
}
__device__ __forceinline__ f32x4 mfmah(half8 a, half8 b, f32x4 c) {
    return __builtin_amdgcn_mfma_f32_16x16x32_f16(a, b, c, 0, 0, 0);
}

// fp16 B-frag of M[kdim x 50] col-slice (RNE). Layout (validated r4-r14):
// lane(r,g) elem e -> B[k=kbase+8g+e][col=c].
__device__ __forceinline__ half8 build_wfrag(const float* __restrict__ M, int kbase,
                                             int kmax, int c, bool cv, int g) {
    unsigned u[4];
#pragma unroll
    for (int q = 0; q < 4; ++q) {
        const int k0 = kbase + 8 * g + 2 * q, k1 = k0 + 1;
        _Float16 v0 = (_Float16)((cv && k0 < kmax) ? M[k0 * HH + c] : 0.0f);
        _Float16 v1 = (_Float16)((cv && k1 < kmax) ? M[k1 * HH + c] : 0.0f);
        u[q] = ((unsigned)__builtin_bit_cast(unsigned short, v1) << 16)
             |  __builtin_bit_cast(unsigned short, v0);
    }
    uint32x4 uu = {u[0], u[1], u[2], u[3]};
    return __builtin_bit_cast(half8, uu);
}

// 8 f32 -> half8 via v_cvt_pkrtz (x path)
__device__ __forceinline__ half8 cvt8(float4 a, float4 b) {
    unsigned u0 = __builtin_bit_cast(unsigned, __builtin_amdgcn_cvt_pkrtz(a.x, a.y));
    unsigned u1 = __builtin_bit_cast(unsigned, __builtin_amdgcn_cvt_pkrtz(a.z, a.w));
    unsigned u2 = __builtin_bit_cast(unsigned, __builtin_amdgcn_cvt_pkrtz(b.x, b.y));
    unsigned u3 = __builtin_bit_cast(unsigned, __builtin_amdgcn_cvt_pkrtz(b.z, b.w));
    uint32x4 uu = {u0, u1, u2, u3};
    return __builtin_bit_cast(half8, uu);
}

// ONE WAVE per block, 16 REAL rows (no M-duplication), all 50 cols.
// 256 blocks = 1 wave/CU: pure latency race, but every instruction now
// serves real work (r12-r14 plateau: 2-rows/wave paid full frag machinery
// for 2 rows -> ~110 VALU-cyc/row; here ~15).
// h round-trip via packed row-pair LDS: u32[rowpair][col] = (row2p lo16,
// row2p+1 hi16). Write: 8 cvt_pkrtz + 8 ds_write_b32 (2-way banks).
// Read: 4 ds_read_b128 (8 contiguous u32 per A-half) + 8 v_perm with
// loop-invariant (r&1) selector. No barrier/waitcnt (in-order DS,
// wave-private, double-buffered). waves_per_eu(1,1): full register
// budget -> no AGPR shuttle (r12/r13 trap).
__global__
__attribute__((amdgpu_flat_work_group_size(64, 64)))
__attribute__((amdgpu_waves_per_eu(1, 1)))
void rnn_fp16(const float* __restrict__ x, const float* __restrict__ W,
              const float* __restrict__ U, const float* __restrict__ b,
              const float* __restrict__ Wd, const float* __restrict__ bd,
              float* __restrict__ out)
{
    __shared__ unsigned hbuf[2][8][PITCH];   // [buf][rowpair][col]

    const int l = threadIdx.x & 63;
    const int r = l & 15;
    const int g = l >> 4;
    const int rb = blockIdx.x * 16;

    // weight frags for all 4 N-tiles (48 VGPR) + persistent bias C (16 VGPR)
    half8 Wf[4], U0[4], U1[4];
    f32x4 biasv[4];
    float wdv[4];
#pragma unroll
    for (int n = 0; n < 4; ++n) {
        const int c = 16 * n + r;
        const bool cv = (c < HH);
        Wf[n] = build_wfrag(W, 0,  FF, c, cv, g);
        U0[n] = build_wfrag(U, 0,  HH, c, cv, g);
        U1[n] = build_wfrag(U, 32, HH, c, cv, g);
        const float bv = cv ? b[c] : 0.0f;
        biasv[n] = (f32x4){bv, bv, bv, bv};
        wdv[n] = cv ? Wd[c] : 0.0f;
    }
    const unsigned psel = (r & 1) ? 0x07060302u : 0x05040100u;   // hi16 : lo16

    const float* xrow = x + (size_t)(rb + r) * TT * FF + 8 * g;

    // nx[n] = biasv + x_t @ W (1 MFMA/tile; off the h path)
    auto do_nx = [&](float4 a, float4 b2, f32x4 (&nx)[4]) {
        half8 xa = cvt8(a, b2);
#pragma unroll
        for (int n = 0; n < 4; ++n) nx[n] = mfmah(xa, Wf[n], biasv[n]);
    };

    // prologue: xc = bias + x_0@W; prefetch x_1 (pa), x_2 (pb)
    f32x4 xc[4], xn[4];
    do_nx(*(const float4*)(xrow), *(const float4*)(xrow + 4), xc);
    float4 pa0 = *(const float4*)(xrow + FF),     pa1 = *(const float4*)(xrow + FF + 4);
    float4 pb0 = *(const float4*)(xrow + 2 * FF), pb1 = *(const float4*)(xrow + 2 * FF + 4);

    float hf[4][4];   // final h: hf[n][i] = h[4g+i][16n+r] (for the head)

    auto step = [&](int t, bool first, f32x4 (&xcur)[4], f32x4 (&xnext)[4],
                    float4& qa, float4& qb) {
        const int buf = t & 1;
        // h_t A-frags: 4 b128 reads + 8 perms (row r, k=8g+e; u32[r>>1][k])
        half8 A0, A1;
        if (!first) {
            const unsigned* base = &hbuf[buf][r >> 1][0];
            uint32x4 w0 = *(const uint32x4*)(base + 8 * g);
            uint32x4 w1 = *(const uint32x4*)(base + 8 * g + 4);
            uint32x4 w2 = *(const uint32x4*)(base + 32 + 8 * g);
            uint32x4 w3 = *(const uint32x4*)(base + 32 + 8 * g + 4);
            uint32x4 a0 = {__builtin_amdgcn_perm(w0[1], w0[0], psel),
                           __builtin_amdgcn_perm(w0[3], w0[2], psel),
                           __builtin_amdgcn_perm(w1[1], w1[0], psel),
                           __builtin_amdgcn_perm(w1[3], w1[2], psel)};
            uint32x4 a1 = {__builtin_amdgcn_perm(w2[1], w2[0], psel),
                           __builtin_amdgcn_perm(w2[3], w2[2], psel),
                           __builtin_amdgcn_perm(w3[1], w3[0], psel),
                           __builtin_amdgcn_perm(w3[3], w3[2], psel)};
            A0 = __builtin_bit_cast(half8, a0);
            A1 = __builtin_bit_cast(half8, a1);
        }
        // x_{t+1}@W (independent of h, fills the read latency) + prefetch t+3
        do_nx(qa, qb, xnext);
        int tn = t + 3; if (tn > TT - 1) tn = TT - 1;
        qa = *(const float4*)(xrow + (size_t)tn * FF);
        qb = *(const float4*)(xrow + (size_t)tn * FF + 4);

        f32x4 tot[4];
        if (!first) {
#pragma unroll
            for (int n = 0; n < 4; ++n)   // serial 2-chain: C stays in MFMA domain
                tot[n] = mfmah(A1, U1[n], mfmah(A0, U0[n], xcur[n]));
        } else {
#pragma unroll
            for (int n = 0; n < 4; ++n) tot[n] = xcur[n];
        }

        // tanh all 16 (every one real), pack row pairs, 8 ds_write_b32
        unsigned* wb = &hbuf[buf ^ 1][0][0];
#pragma unroll
        for (int n = 0; n < 4; ++n) {
            hf[n][0] = fast_tanh(tot[n][0]);
            hf[n][1] = fast_tanh(tot[n][1]);
            hf[n][2] = fast_tanh(tot[n][2]);
            hf[n][3] = fast_tanh(tot[n][3]);
            wb[(2 * g + 0) * PITCH + 16 * n + r] = __builtin_bit_cast(
                unsigned, __builtin_amdgcn_cvt_pkrtz(hf[n][0], hf[n][1]));
            wb[(2 * g + 1) * PITCH + 16 * n + r] = __builtin_bit_cast(
                unsigned, __builtin_amdgcn_cvt_pkrtz(hf[n][2], hf[n][3]));
        }
        // no barrier, no waitcnt: wave-private in-order DS
    };

    step(0, true, xc, xn, pa0, pa1);
    for (int t = 1; t < TT - 1; t += 2) {
        step(t,     false, xn, xc, pb0, pb1);
        step(t + 1, false, xc, xn, pa0, pa1);
    }
    step(TT - 1, false, xn, xc, pb0, pb1);

    // head: out[4g+i] = relu(sum_n hf[n][i]*Wd[16n+r] reduced over r + bd)
    const float bdv = bd[0];
#pragma unroll
    for (int i = 0; i < 4; ++i) {
        float p = hf[0][i] * wdv[0] + hf[1][i] * wdv[1]
                + hf[2][i] * wdv[2] + hf[3][i] * wdv[3];
        p += __shfl_xor(p, 1);
        p += __shfl_xor(p, 2);
        p += __shfl_xor(p, 4);
        p += __shfl_xor(p, 8);
        if (r == 0) out[rb + 4 * g + i] = fmaxf(p + bdv, 0.0f);
    }
}

extern "C" void kernel_launch(void* const* d_in, const int* in_sizes, int n_in,
                              void* d_out, int out_size, void* d_ws, size_t ws_size,
                              hipStream_t stream) {
    const float* x  = (const float*)d_in[0];
    const float* W  = (const float*)d_in[1];
    const float* U  = (const float*)d_in[2];
    const float* b  = (const float*)d_in[3];
    const float* Wd = (const float*)d_in[4];
    const float* bd = (const float*)d_in[5];
    float* out = (float*)d_out;
    const int B = out_size;                       // 4096
    dim3 grid(B / 16), block(64);                 // 256 blocks, 1 wave, 16 rows
    hipLaunchKernelGGL(rnn_fp16, grid, block, 0, stream,
                       x, W, U, b, Wd, bd, out);
    (void)d_ws; (void)ws_size; (void)in_sizes; (void)n_in;
}

// Round 16
// 65.420 us; speedup vs baseline: 1.9224x; 1.9224x over previous
//
#include <hip/hip_runtime.h>

#define TT 200
#define FF 32
#define HH 50
#define NCH 13   // ceil(TT/16) chunks of 16 timesteps

typedef _Float16 half8 __attribute__((ext_vector_type(8)));   // 8 f16 = 4 VGPR
typedef __attribute__((ext_vector_type(4))) float f32x4;
typedef __attribute__((ext_vector_type(4))) unsigned int uint32x4;

// tanh(x) = 1 - 2/(exp2(2*log2e*x)+1)
__device__ __forceinline__ float fast_tanh(float x) {
    float e = exp2f(2.885390082f * x);
    return fmaf(-2.0f, __builtin_amdgcn_rcpf(e + 1.0f), 1.0f);
}
__device__ __forceinline__ f32x4 mfmah(half8 a, half8 b, f32x4 c) {
    return __builtin_amdgcn_mfma_f32_16x16x32_f16(a, b, c, 0, 0, 0);
}

// fp16 B-frag of M[kdim x 50] col-slice (RNE). Layout (validated r4-r15):
// lane(r,g) elem e -> B[k=kbase+8g+e][col=c].
__device__ __forceinline__ half8 build_wfrag(const float* __restrict__ M, int kbase,
                                             int kmax, int c, bool cv, int g) {
    unsigned u[4];
#pragma unroll
    for (int q = 0; q < 4; ++q) {
        const int k0 = kbase + 8 * g + 2 * q, k1 = k0 + 1;
        _Float16 v0 = (_Float16)((cv && k0 < kmax) ? M[k0 * HH + c] : 0.0f);
        _Float16 v1 = (_Float16)((cv && k1 < kmax) ? M[k1 * HH + c] : 0.0f);
        u[q] = ((unsigned)__builtin_bit_cast(unsigned short, v1) << 16)
             |  __builtin_bit_cast(unsigned short, v0);
    }
    uint32x4 uu = {u[0], u[1], u[2], u[3]};
    return __builtin_bit_cast(half8, uu);
}

// 8 f32 -> half8 via v_cvt_pkrtz (x-GEMM A path)
__device__ __forceinline__ half8 cvt8(float4 a, float4 b) {
    unsigned u0 = __builtin_bit_cast(unsigned, __builtin_amdgcn_cvt_pkrtz(a.x, a.y));
    unsigned u1 = __builtin_bit_cast(unsigned, __builtin_amdgcn_cvt_pkrtz(a.z, a.w));
    unsigned u2 = __builtin_bit_cast(unsigned, __builtin_amdgcn_cvt_pkrtz(b.x, b.y));
    unsigned u3 = __builtin_bit_cast(unsigned, __builtin_amdgcn_cvt_pkrtz(b.z, b.w));
    uint32x4 uu = {u0, u1, u2, u3};
    return __builtin_bit_cast(half8, uu);
}

// ONE WAVE per block, 2 real rows (M-dup x8), 2048 blocks = 2 waves/SIMD
// (r13 shell) with the fixed cost F slashed (r15 post-mortem: wall =
// max(per-SIMD issue, exposed path); TLP needs 2/SIMD -> 2 rows/wave;
// lever = F):
//  1. x-GEMM batched per 16-timestep chunk (A rows = timesteps, no dup
//     waste): 8 MFMA + 4 gloads + cvts per 16 steps, staged in LDS as
//     f32 (numerics = r13's f32 xacc). Loads prefetched 16 steps
//     (~2900 cyc) ahead -> global latency structurally hidden.
//  2. h stored as plain f16 [2][64]: A-frag = 1 ds_read_b128 per K-half
//     (broadcast, conflict-free), NO perms, no packing.
//  3. xw added POST-select as scalar (2 ds_read_b32): h-MFMAs use a
//     persistent zero C, serial chains stay in the MFMA domain; only 8
//     scalars/step cross to VALU.
// No barriers, no waitcnt anywhere in the loop (wave-private in-order DS).
__global__
__attribute__((amdgpu_flat_work_group_size(64, 64)))
__attribute__((amdgpu_waves_per_eu(2, 2)))
void rnn_fp16(const float* __restrict__ x, const float* __restrict__ W,
              const float* __restrict__ U, const float* __restrict__ b,
              const float* __restrict__ Wd, const float* __restrict__ bd,
              float* __restrict__ out)
{
    __shared__ float xw[2][16][2][64];    // [chunk parity][t&15][row][col] 16 KB
    __shared__ _Float16 hl[2][2][64];     // [buf][row][col] 512 B

    const int l = threadIdx.x & 63;
    const int r = l & 15;
    const int g = l >> 4;
    const int rl = r & 1;                 // real row (M-dup x8)
    const int rb = blockIdx.x * 2;
    const bool gs1 = (g & 1) != 0, gs2 = (g & 2) != 0;
    const int cg = 16 * g + r;            // this lane's h column (0..63)

    // weight frags (48 VGPR) + bias C (16, chunk-GEMM only) + zero C (4)
    half8 Wf[4], U0[4], U1[4];
    f32x4 biasv[4];
#pragma unroll
    for (int n = 0; n < 4; ++n) {
        const int c = 16 * n + r;
        const bool cv = (c < HH);
        Wf[n] = build_wfrag(W, 0,  FF, c, cv, g);
        U0[n] = build_wfrag(U, 0,  HH, c, cv, g);
        U1[n] = build_wfrag(U, 32, HH, c, cv, g);
        const float bv = cv ? b[c] : 0.0f;
        biasv[n] = (f32x4){bv, bv, bv, bv};
    }
    const f32x4 kzero = {0.0f, 0.0f, 0.0f, 0.0f};
    const float wd = (cg < HH) ? Wd[cg] : 0.0f;

    const float* x0 = x + (size_t)(rb + 0) * TT * FF;
    const float* x1 = x + (size_t)(rb + 1) * TT * FF;

    // chunk staging registers (held 16 steps between load and compute)
    float4 r0a, r0b, r1a, r1b;
    auto chunk_load = [&](int cc) {
        int tt = 16 * cc + r; if (tt > TT - 1) tt = TT - 1;   // clamp tail
        const float* p0 = x0 + (size_t)tt * FF + 8 * g;
        const float* p1 = x1 + (size_t)tt * FF + 8 * g;
        r0a = *(const float4*)p0; r0b = *(const float4*)(p0 + 4);
        r1a = *(const float4*)p1; r1b = *(const float4*)(p1 + 4);
    };
    // xw[t] = bias + x_t @ W for 16 timesteps: M=timesteps GEMM, C-layout
    // lane(r,g) elem i -> t_local=4g+i, col=16n+r  -> LDS f32
    auto chunk_compute = [&](int cc) {
        half8 a0 = cvt8(r0a, r0b);
        half8 a1 = cvt8(r1a, r1b);
        const int par = cc & 1;
#pragma unroll
        for (int n = 0; n < 4; ++n) {
            f32x4 c0 = mfmah(a0, Wf[n], biasv[n]);
            f32x4 c1 = mfmah(a1, Wf[n], biasv[n]);
#pragma unroll
            for (int i = 0; i < 4; ++i) {
                xw[par][4 * g + i][0][16 * n + r] = c0[i];
                xw[par][4 * g + i][1][16 * n + r] = c1[i];
            }
        }
    };

    // prologue: chunk 0 computed; chunk 1 loads in flight; h=0
    chunk_load(0);
    chunk_compute(0);
    chunk_load(1);
    ((unsigned*)hl)[l] = 0u;              // zero both h buffers (512 B)
    ((unsigned*)hl)[64 + l] = 0u;

    float hf0 = 0.0f, hf1 = 0.0f;

    for (int t = 0; t < TT; ++t) {
        const int buf = t & 1, c = t >> 4, tl = t & 15, par = c & 1;

        // h_t A-frags: broadcast b128 reads, no perms (rows M-dup'd)
        const _Float16* hp = &hl[buf][rl][0];
        half8 A0 = *(const half8*)(hp + 8 * g);          // k 0..31
        half8 A1 = *(const half8*)(hp + 32 + 8 * g);     // k 32..63 (pad 0)

        f32x4 tot[4];
#pragma unroll
        for (int n = 0; n < 4; ++n)       // serial 2-chain, C = persistent zero
            tot[n] = mfmah(A1, U1[n], mfmah(A0, U0[n], kzero));

        // mid-chunk: build next chunk's xw (regs loaded 16 steps ago),
        // then issue loads for the chunk after (16-step latency cover)
        if (tl == 8) {
            if (c + 1 < NCH) chunk_compute(c + 1);
            if (c + 2 < NCH) chunk_load(c + 2);
        }

        // select tile g (lane owns col cg), add xw, tanh, publish
        float a0 = gs1 ? tot[1][0] : tot[0][0];
        float a1 = gs1 ? tot[1][1] : tot[0][1];
        float c0 = gs1 ? tot[3][0] : tot[2][0];
        float c1 = gs1 ? tot[3][1] : tot[2][1];
        float m0 = gs2 ? c0 : a0;
        float m1 = gs2 ? c1 : a1;
        m0 += xw[par][tl][0][cg];         // conflict-free: 64 consecutive f32
        m1 += xw[par][tl][1][cg];
        hf0 = fast_tanh(m0);
        hf1 = fast_tanh(m1);
        hl[buf ^ 1][0][cg] = (_Float16)hf0;   // RNE; 2 lanes/bank: free
        hl[buf ^ 1][1][cg] = (_Float16)hf1;
        // no barrier, no waitcnt: wave-private in-order DS
    }

    // head: out[row i] = relu(sum_c h[i][c]*Wd[c] + bd)
    float p0 = hf0 * wd, p1 = hf1 * wd;
#pragma unroll
    for (int m = 1; m <= 32; m <<= 1) {
        p0 += __shfl_xor(p0, m);
        p1 += __shfl_xor(p1, m);
    }
    if (l == 0) {
        const float bdv = bd[0];
        out[rb + 0] = fmaxf(p0 + bdv, 0.0f);
        out[rb + 1] = fmaxf(p1 + bdv, 0.0f);
    }
}

extern "C" void kernel_launch(void* const* d_in, const int* in_sizes, int n_in,
                              void* d_out, int out_size, void* d_ws, size_t ws_size,
                              hipStream_t stream) {
    const float* x  = (const float*)d_in[0];
    const float* W  = (const float*)d_in[1];
    const float* U  = (const float*)d_in[2];
    const float* b  = (const float*)d_in[3];
    const float* Wd = (const float*)d_in[4];
    const float* bd = (const float*)d_in[5];
    float* out = (float*)d_out;
    const int B = out_size;                       // 4096
    dim3 grid(B / 2), block(64);                  // 2048 blocks, 1 wave, 2 rows
    hipLaunchKernelGGL(rnn_fp16, grid, block, 0, stream,
                       x, W, U, b, Wd, bd, out);
    (void)d_ws; (void)ws_size; (void)in_sizes; (void)n_in;
}

// Round 17
// 65.168 us; speedup vs baseline: 1.9299x; 1.0039x over previous
//
#include <hip/hip_runtime.h>

#define TT 200
#define FF 32
#define HH 50
#define NCH 13   // ceil(TT/16) chunks of 16 timesteps

typedef _Float16 half8 __attribute__((ext_vector_type(8)));   // 8 f16 = 4 VGPR
typedef __attribute__((ext_vector_type(4))) float f32x4;
typedef __attribute__((ext_vector_type(4))) unsigned int uint32x4;

// tanh(x) = 1 - 2/(exp2(2*log2e*x)+1)
__device__ __forceinline__ float fast_tanh(float x) {
    float e = exp2f(2.885390082f * x);
    return fmaf(-2.0f, __builtin_amdgcn_rcpf(e + 1.0f), 1.0f);
}
__device__ __forceinline__ f32x4 mfmah(half8 a, half8 b, f32x4 c) {
    return __builtin_amdgcn_mfma_f32_16x16x32_f16(a, b, c, 0, 0, 0);
}

// fp16 B-frag of M[kdim x 50] col-slice (RNE). Layout (validated r4-r16):
// lane(r,g) elem e -> B[k=kbase+8g+e][col=c].
__device__ __forceinline__ half8 build_wfrag(const float* __restrict__ M, int kbase,
                                             int kmax, int c, bool cv, int g) {
    unsigned u[4];
#pragma unroll
    for (int q = 0; q < 4; ++q) {
        const int k0 = kbase + 8 * g + 2 * q, k1 = k0 + 1;
        _Float16 v0 = (_Float16)((cv && k0 < kmax) ? M[k0 * HH + c] : 0.0f);
        _Float16 v1 = (_Float16)((cv && k1 < kmax) ? M[k1 * HH + c] : 0.0f);
        u[q] = ((unsigned)__builtin_bit_cast(unsigned short, v1) << 16)
             |  __builtin_bit_cast(unsigned short, v0);
    }
    uint32x4 uu = {u[0], u[1], u[2], u[3]};
    return __builtin_bit_cast(half8, uu);
}

// 8 f32 -> half8 via v_cvt_pkrtz (x-GEMM A path)
__device__ __forceinline__ half8 cvt8(float4 a, float4 b) {
    unsigned u0 = __builtin_bit_cast(unsigned, __builtin_amdgcn_cvt_pkrtz(a.x, a.y));
    unsigned u1 = __builtin_bit_cast(unsigned, __builtin_amdgcn_cvt_pkrtz(a.z, a.w));
    unsigned u2 = __builtin_bit_cast(unsigned, __builtin_amdgcn_cvt_pkrtz(b.x, b.y));
    unsigned u3 = __builtin_bit_cast(unsigned, __builtin_amdgcn_cvt_pkrtz(b.z, b.w));
    uint32x4 uu = {u0, u1, u2, u3};
    return __builtin_bit_cast(half8, uu);
}

// r16 shell (1 wave/block, 2 real rows M-dup x8, 2048 blocks = 2 waves/SIMD,
// chunk-batched x-GEMM, f16 h in LDS, barrier/waitcnt-free) with the VALU
// cut toward the MFMA floor (r16 post-mortem: 95% issue-saturated; VALU 373
// vs MFMA 266 cyc/SIMD/step; ~40 instr/step of AGPR shuttle + addressing):
//  1. asm "+v" on every MFMA accumulator -> regalloc puts C/D in arch VGPRs
//     (legal on gfx950 unified file), deleting the v_accvgpr_read traffic
//     on select/store consumption.
//  2. full 16-step unroll per chunk: tl/buf compile-time -> immediate LDS
//     offsets, no per-step branch, one xw pointer per chunk.
__global__
__attribute__((amdgpu_flat_work_group_size(64, 64)))
__attribute__((amdgpu_waves_per_eu(2, 2)))
void rnn_fp16(const float* __restrict__ x, const float* __restrict__ W,
              const float* __restrict__ U, const float* __restrict__ b,
              const float* __restrict__ Wd, const float* __restrict__ bd,
              float* __restrict__ out)
{
    __shared__ float xw[2][16][2][64];    // [chunk parity][t&15][row][col] 16 KB
    __shared__ _Float16 hl[2][2][64];     // [buf][row][col] 512 B

    const int l = threadIdx.x & 63;
    const int r = l & 15;
    const int g = l >> 4;
    const int rl = r & 1;                 // real row (M-dup x8)
    const int rb = blockIdx.x * 2;
    const bool gs1 = (g & 1) != 0, gs2 = (g & 2) != 0;
    const int cg = 16 * g + r;            // this lane's h column (0..63)

    // weight frags (48 VGPR) + bias C (16, chunk-GEMM only) + zero C (4)
    half8 Wf[4], U0[4], U1[4];
    f32x4 biasv[4];
#pragma unroll
    for (int n = 0; n < 4; ++n) {
        const int c = 16 * n + r;
        const bool cv = (c < HH);
        Wf[n] = build_wfrag(W, 0,  FF, c, cv, g);
        U0[n] = build_wfrag(U, 0,  HH, c, cv, g);
        U1[n] = build_wfrag(U, 32, HH, c, cv, g);
        const float bv = cv ? b[c] : 0.0f;
        biasv[n] = (f32x4){bv, bv, bv, bv};
    }
    const f32x4 kzero = {0.0f, 0.0f, 0.0f, 0.0f};
    const float wd = (cg < HH) ? Wd[cg] : 0.0f;

    const float* x0 = x + (size_t)(rb + 0) * TT * FF;
    const float* x1 = x + (size_t)(rb + 1) * TT * FF;

    // chunk staging registers (held 16 steps between load and compute)
    float4 r0a, r0b, r1a, r1b;
    auto chunk_load = [&](int cc) {
        int tt = 16 * cc + r; if (tt > TT - 1) tt = TT - 1;   // clamp tail
        const float* p0 = x0 + (size_t)tt * FF + 8 * g;
        const float* p1 = x1 + (size_t)tt * FF + 8 * g;
        r0a = *(const float4*)p0; r0b = *(const float4*)(p0 + 4);
        r1a = *(const float4*)p1; r1b = *(const float4*)(p1 + 4);
    };
    // xw[t] = bias + x_t @ W for 16 timesteps (M = timesteps GEMM) -> LDS f32
    auto chunk_compute = [&](int cc) {
        half8 a0 = cvt8(r0a, r0b);
        half8 a1 = cvt8(r1a, r1b);
        const int par = cc & 1;
#pragma unroll
        for (int n = 0; n < 4; ++n) {
            f32x4 c0 = mfmah(a0, Wf[n], biasv[n]);
            f32x4 c1 = mfmah(a1, Wf[n], biasv[n]);
            asm volatile("" : "+v"(c0), "+v"(c1));   // keep C/D in arch VGPRs
#pragma unroll
            for (int i = 0; i < 4; ++i) {
                xw[par][4 * g + i][0][16 * n + r] = c0[i];
                xw[par][4 * g + i][1][16 * n + r] = c1[i];
            }
        }
    };

    // prologue: chunk 0 computed; chunk 1 loads in flight; h=0
    chunk_load(0);
    chunk_compute(0);
    chunk_load(1);
    ((unsigned*)hl)[l] = 0u;              // zero both h buffers (512 B)
    ((unsigned*)hl)[64 + l] = 0u;

    float hf0 = 0.0f, hf1 = 0.0f;

    // 12 full 16-step chunks + 8-step tail, inner loops fully unrolled so
    // tl and buf are compile-time (immediate LDS offsets, no branches)
    for (int c = 0; c < NCH; ++c) {
        const float* xwp = (c & 1) ? &xw[1][0][0][cg] : &xw[0][0][0][cg];
        const int nsteps = (c == NCH - 1) ? (TT - 16 * (NCH - 1)) : 16;
#pragma unroll
        for (int tl = 0; tl < 16; ++tl) {
            if (tl >= nsteps) break;      // tail: compile-time trip known? no:
                                          // nsteps runtime only in last chunk;
                                          // unrolled body guarded per tl
            const int buf = tl & 1;
            // h_t A-frags: broadcast b128 reads, immediate offsets
            const _Float16* hp = &hl[buf][rl][0];
            half8 A0 = *(const half8*)(hp + 8 * g);          // k 0..31
            half8 A1 = *(const half8*)(hp + 32 + 8 * g);     // k 32..63 (pad 0)

            f32x4 tot[4];
#pragma unroll
            for (int n = 0; n < 4; ++n)   // serial 2-chain, persistent zero C
                tot[n] = mfmah(A1, U1[n], mfmah(A0, U0[n], kzero));
            asm volatile("" : "+v"(tot[0]), "+v"(tot[1]), "+v"(tot[2]), "+v"(tot[3]));

            // mid-chunk: next chunk's xw GEMM + loads for the one after
            if (tl == 8) {
                if (c + 1 < NCH) chunk_compute(c + 1);
                if (c + 2 < NCH) chunk_load(c + 2);
            }

            // select tile g, add xw (immediate-offset reads), tanh, publish
            float a0 = gs1 ? tot[1][0] : tot[0][0];
            float a1 = gs1 ? tot[1][1] : tot[0][1];
            float c0 = gs1 ? tot[3][0] : tot[2][0];
            float c1 = gs1 ? tot[3][1] : tot[2][1];
            float m0 = gs2 ? c0 : a0;
            float m1 = gs2 ? c1 : a1;
            m0 += xwp[tl * 128];          // xw[par][tl][0][cg]
            m1 += xwp[tl * 128 + 64];     // xw[par][tl][1][cg]
            hf0 = fast_tanh(m0);
            hf1 = fast_tanh(m1);
            hl[buf ^ 1][0][cg] = (_Float16)hf0;   // 2-way banks: free
            hl[buf ^ 1][1][cg] = (_Float16)hf1;
            // no barrier, no waitcnt: wave-private in-order DS
        }
    }

    // head: out[row i] = relu(sum_c h[i][c]*Wd[c] + bd)
    float p0 = hf0 * wd, p1 = hf1 * wd;
#pragma unroll
    for (int m = 1; m <= 32; m <<= 1) {
        p0 += __shfl_xor(p0, m);
        p1 += __shfl_xor(p1, m);
    }
    if (l == 0) {
        const float bdv = bd[0];
        out[rb + 0] = fmaxf(p0 + bdv, 0.0f);
        out[rb + 1] = fmaxf(p1 + bdv, 0.0f);
    }
}

extern "C" void kernel_launch(void* const* d_in, const int* in_sizes, int n_in,
                              void* d_out, int out_size, void* d_ws, size_t ws_size,
                              hipStream_t stream) {
    const float* x  = (const float*)d_in[0];
    const float* W  = (const float*)d_in[1];
    const float* U  = (const float*)d_in[2];
    const float* b  = (const float*)d_in[3];
    const float* Wd = (const float*)d_in[4];
    const float* bd = (const float*)d_in[5];
    float* out = (float*)d_out;
    const int B = out_size;                       // 4096
    dim3 grid(B / 2), block(64);                  // 2048 blocks, 1 wave, 2 rows
    hipLaunchKernelGGL(rnn_fp16, grid, block, 0, stream,
                       x, W, U, b, Wd, bd, out);
    (void)d_ws; (void)ws_size; (void)in_sizes; (void)n_in;
}